// Round 8
// baseline (167.751 us; speedup 1.0000x reference)
//
#include <hip/hip_runtime.h>

// Segment-mean of subtoken embeddings (sorted per-row segment ids) -> token means.
//
// Round-8: round-7 (NT loads+stores, tiny blocks) + TWO TOKENS PER BLOCK.
// r7 post-mortem: NT loads confirmed the hit/miss-mix mechanism (-7.7us);
// residual phase-2 gap vs pure-stream BW (~4.0 vs 6.3 TB/s) attributed to
// per-block prologue (kernarg s_load -> dependent pairs load -> tiny payload)
// paid once per token, 26% of blocks being prologue-only (cnt=0).
// Fix: one int4 load gives bounds for 2 tokens (halves blocks + pairs loads);
// the two accumulation chains are interleaved so token-B loads issue before
// token-A's waitcnt (B latency hides under A). Per-token accumulation order
// remains strictly sequential (absmax must stay 0).

typedef float f32x4_v __attribute__((ext_vector_type(4)));

__global__ void bounds_pairs_kernel(const int* __restrict__ seg,
                                    const int* __restrict__ num_tokens_p,
                                    int2* __restrict__ pairs,   // [B*T] global-row bounds
                                    int BS_total,               // B*S
                                    int BT) {                   // B*T
  const int T = num_tokens_p[0];
  const int B = BT / T;
  const int S = BS_total / B;
  const int idx = blockIdx.x * blockDim.x + threadIdx.x;
  if (idx >= BS_total) return;
  const int b = idx / S;
  const int s = idx - b * S;
  const int cur = seg[idx];
  const int prev = (s == 0) ? -1 : seg[idx - 1];
  int2* __restrict__ prow = pairs + (size_t)b * T;

  for (int t = prev + 1; t <= cur; ++t) {
    prow[t].x = idx;                 // lo(t): global row index
    if (t > 0) prow[t - 1].y = idx;  // hi(t-1) = lo(t)
  }
  if (s == S - 1) {
    const int end = b * S + S;
    for (int t = cur + 1; t <= T; ++t) {
      if (t < T) prow[t].x = end;
      prow[t - 1].y = end;
    }
  }
}

// Two tokens per block, 192 threads (3 waves), lane owns one float4 column.
__global__ void __launch_bounds__(192) seg_mean_tok2_d768(
    const float* __restrict__ hs,      // [B, S, 768]
    const int2*  __restrict__ pairs,   // [B*T]
    float*       __restrict__ out,     // [B, T, 768]
    int BT) {
  const int g0 = blockIdx.x * 2;
  const int d4 = threadIdx.x;          // [0, 192)
  const f32x4_v* __restrict__ hsv = (const f32x4_v*)hs;

  if (g0 + 1 < BT) {
    // One 16B load covers both tokens' bounds (pairs 16B-aligned in d_ws).
    const int4 pp = *((const int4*)pairs + blockIdx.x);
    const int cA = pp.y - pp.x;
    const int cB = pp.w - pp.z;

    f32x4_v oA = {0.f, 0.f, 0.f, 0.f};
    f32x4_v oB = oA;

    if ((cA | cB) != 0) {
      const f32x4_v* __restrict__ pA = hsv + (size_t)pp.x * 192 + d4;
      const f32x4_v* __restrict__ pB = hsv + (size_t)pp.z * 192 + d4;
      f32x4_v accA = {0.f, 0.f, 0.f, 0.f};
      f32x4_v accB = accA;

      const int m = (cA > cB) ? cA : cB;
      for (int r = 0; r < m; ++r) {    // block-uniform branches
        f32x4_v a, b;
        const bool hA = (r < cA);
        const bool hB = (r < cB);
        if (hA) a = __builtin_nontemporal_load(pA);   // issue A
        if (hB) b = __builtin_nontemporal_load(pB);   // issue B before A's wait
        if (hA) { accA = accA + a; pA += 192; }       // sequential order per token
        if (hB) { accB = accB + b; pB += 192; }
      }
      if (cA > 0) oA = accA * (1.0f / (float)cA);
      if (cB > 0) oB = accB * (1.0f / (float)cB);
    }

    f32x4_v* __restrict__ q = (f32x4_v*)out + (size_t)g0 * 192 + d4;
    __builtin_nontemporal_store(oA, q);
    __builtin_nontemporal_store(oB, q + 192);
  } else if (g0 < BT) {
    // Odd-BT tail: single token.
    const int2 lh = pairs[g0];
    const int cnt = lh.y - lh.x;
    f32x4_v acc = {0.f, 0.f, 0.f, 0.f};
    const f32x4_v* __restrict__ p = hsv + (size_t)lh.x * 192 + d4;
    for (int r = 0; r < cnt; ++r) {
      acc = acc + __builtin_nontemporal_load(p);
      p += 192;
    }
    const float inv = (cnt > 0) ? (1.0f / (float)cnt) : 0.0f;
    __builtin_nontemporal_store(acc * inv,
                                (f32x4_v*)out + (size_t)g0 * 192 + d4);
  }
}

// Generic-D fallback (D % 4 == 0): one wave per token, column-strided.
__global__ void __launch_bounds__(256) seg_mean_generic(
    const float* __restrict__ hs,
    const int2*  __restrict__ pairs,
    float*       __restrict__ out,
    int BT,
    int dv4) {
  const int wave = threadIdx.x >> 6;
  const int lane = threadIdx.x & 63;
  const int gstride = gridDim.x * 4;

  for (int g = blockIdx.x * 4 + wave; g < BT; g += gstride) {
    const int2 lh = pairs[g];
    const int cnt = lh.y - lh.x;
    const float inv = (cnt > 0) ? (1.0f / (float)cnt) : 0.0f;

    for (int c = lane; c < dv4; c += 64) {
      const float4* __restrict__ p = (const float4*)hs + (size_t)lh.x * dv4 + c;
      float4 acc = make_float4(0.f, 0.f, 0.f, 0.f);
      for (int r = 0; r < cnt; ++r) {
        float4 v = *p;
        acc.x += v.x; acc.y += v.y; acc.z += v.z; acc.w += v.w;
        p += dv4;
      }
      ((float4*)(out + (size_t)g * (dv4 * 4)))[c] =
          make_float4(acc.x * inv, acc.y * inv, acc.z * inv, acc.w * inv);
    }
  }
}

// Workspace-too-small fallback (correctness only).
__global__ void __launch_bounds__(192) seg_mean_search_kernel(
    const float* __restrict__ hs,
    const int* __restrict__ seg,
    const int* __restrict__ num_tokens_p,
    float* __restrict__ out,
    int BS_total,
    int D) {
  const int T = num_tokens_p[0];
  const int BT = gridDim.x;
  const int S = (int)(((long long)BS_total * T) / BT);
  const int b = blockIdx.x / T;
  const int t = blockIdx.x - b * T;
  const int* __restrict__ row = seg + (size_t)b * S;

  int lo = 0, n = S;
  while (n > 0) {
    int half = n >> 1;
    int mid = lo + half;
    if (row[mid] < t) { lo = mid + 1; n -= half + 1; } else { n = half; }
  }
  int hi = lo; n = S - lo;
  while (n > 0) {
    int half = n >> 1;
    int mid = hi + half;
    if (row[mid] < t + 1) { hi = mid + 1; n -= half + 1; } else { n = half; }
  }
  const int cnt = hi - lo;

  const int d4 = threadIdx.x;
  const int rowstride4 = D >> 2;
  const float4* __restrict__ p =
      (const float4*)(hs + ((size_t)b * S + lo) * D) + d4;

  float4 acc = make_float4(0.f, 0.f, 0.f, 0.f);
  for (int s = 0; s < cnt; ++s) {
    float4 v = p[(size_t)s * rowstride4];
    acc.x += v.x; acc.y += v.y; acc.z += v.z; acc.w += v.w;
  }
  const float inv = (cnt > 0) ? (1.0f / (float)cnt) : 0.0f;
  float4 o = make_float4(acc.x * inv, acc.y * inv, acc.z * inv, acc.w * inv);
  ((float4*)(out + (size_t)blockIdx.x * D))[d4] = o;
}

extern "C" void kernel_launch(void* const* d_in, const int* in_sizes, int n_in,
                              void* d_out, int out_size, void* d_ws, size_t ws_size,
                              hipStream_t stream) {
  const float* hs = (const float*)d_in[0];
  const int* seg = (const int*)d_in[1];
  const int* num_tokens_p = (const int*)d_in[2];
  float* out = (float*)d_out;

  const int BS_total = in_sizes[1];            // B*S
  const int D = in_sizes[0] / in_sizes[1];     // 768
  const int BT = out_size / D;                 // B*T

  const size_t ws_needed = (size_t)8 * (size_t)BT;   // int2 per token

  if (ws_size >= ws_needed) {
    int2* pairs = (int2*)d_ws;

    const int threads1 = 256;
    const int grid1 = (BS_total + threads1 - 1) / threads1;
    hipLaunchKernelGGL(bounds_pairs_kernel, dim3(grid1), dim3(threads1), 0, stream,
                       seg, num_tokens_p, pairs, BS_total, BT);

    if (D == 768) {
      const int grid2 = (BT + 1) / 2;
      hipLaunchKernelGGL(seg_mean_tok2_d768, dim3(grid2), dim3(192), 0, stream,
                         hs, pairs, out, BT);
    } else {
      const int needBlocks = (BT + 3) / 4;
      const int grid2 = (needBlocks < 2048) ? needBlocks : 2048;
      hipLaunchKernelGGL(seg_mean_generic, dim3(grid2), dim3(256), 0,
                         stream, hs, pairs, out, BT, D / 4);
    }
  } else {
    hipLaunchKernelGGL(seg_mean_search_kernel, dim3(BT), dim3(D / 4), 0, stream,
                       hs, seg, num_tokens_p, out, BS_total, D);
  }
}